// Round 9
// baseline (440.475 us; speedup 1.0000x reference)
//
#include <hip/hip_runtime.h>
#include <hip/hip_bf16.h>

typedef __hip_bfloat16 bf16;

#define ROWS 204800
#define N_INV (1.0f / 204800.0f)

// --- static device scratch (d_ws proved too small; never touch it) ----------
__device__ float g_stats[256];            // sum1[64] sumsq1[64] sum2[32] sumsq2[32]
__device__ bf16  g_E1_0b[100000 * 64];    // 12.8 MB: emb0 @ W1_0^T in bf16
__device__ float g_E1_1[1000 * 64];
__device__ float g_E1_2[100 * 64];
__device__ float g_E1_3[50 * 64];
__device__ float g_U[8 * 64];
__device__ float g_Vb[64];
__device__ float g_bn1[128];              // a1[64], c1[64]
__device__ float g_bn2[64];               // a2[32], c2[32]
__device__ bf16  g_h1p[ROWS * 64];        // 26.2 MB bf16 h1_pre
__device__ bf16  g_h2p[ROWS * 32];        // 13.1 MB bf16 h2_pre

__device__ __forceinline__ int clampi(int v, int hi) {
    return v < 0 ? 0 : (v > hi ? hi : v);
}
__device__ __forceinline__ float rl_f(float v, int l) {
    return __uint_as_float((unsigned int)__builtin_amdgcn_readlane((int)__float_as_uint(v), l));
}
__device__ __forceinline__ float us2f(unsigned short u) {
    return __uint_as_float(((unsigned int)u) << 16);
}

// ---------------------------------------------------------------------------
// Kernel A: E1_t = emb_t @ W1_t^T (t=1..3), U = cont_w @ W1_cont^T,
// Vb = b1 + sum_j cont_b[j] @ W1_cont_j^T. Block 1150 zeroes the stat block.
// ---------------------------------------------------------------------------
__global__ __launch_bounds__(64) void precompute_kernel(
    const float* __restrict__ emb1, const float* __restrict__ emb2, const float* __restrict__ emb3,
    const float* __restrict__ cont_w, const float* __restrict__ cont_b,
    const float* __restrict__ w1, const float* __restrict__ b1)
{
    int b = blockIdx.x;
    int k = threadIdx.x;
    __shared__ float row[32];

    if (b < 1150) {
        const float* tab; float* out; int i, colOff;
        if (b < 1000)      { tab = emb1; out = g_E1_1; i = b;        colOff = 32; }
        else if (b < 1100) { tab = emb2; out = g_E1_2; i = b - 1000; colOff = 64; }
        else               { tab = emb3; out = g_E1_3; i = b - 1100; colOff = 96; }
        if (k < 32) row[k] = tab[i * 32 + k];
        __syncthreads();
        const float* wr = w1 + k * 384 + colOff;
        float acc = 0.f;
        #pragma unroll
        for (int d = 0; d < 32; ++d) acc = fmaf(row[d], wr[d], acc);
        out[i * 64 + k] = acc;
    } else {
        g_stats[k]       = 0.f;
        g_stats[k + 64]  = 0.f;
        g_stats[k + 128] = 0.f;
        g_stats[k + 192] = 0.f;

        float vb = b1[k];
        #pragma unroll
        for (int j = 0; j < 8; ++j) {
            const float* wr = w1 + k * 384 + (4 + j) * 32;
            float u = 0.f;
            #pragma unroll
            for (int d = 0; d < 32; ++d) {
                float w = wr[d];
                u  = fmaf(cont_w[j * 32 + d], w, u);
                vb = fmaf(cont_b[j * 32 + d], w, vb);
            }
            g_U[j * 64 + k] = u;
        }
        g_Vb[k] = vb;
    }
}

// ---------------------------------------------------------------------------
// e10: E1_0 = emb0 @ W1_0^T  (100000 x 64), stored bf16. Wave per row.
// ---------------------------------------------------------------------------
__global__ __launch_bounds__(256) void e10_kernel(
    const float* __restrict__ emb0, const float* __restrict__ w1)
{
    int lane = threadIdx.x & 63;
    int wv   = threadIdx.x >> 6;

    float w1col[32];
    {
        const float4* wr = (const float4*)(w1 + lane * 384);
        #pragma unroll
        for (int q = 0; q < 8; ++q) {
            float4 v = wr[q];
            w1col[4*q+0] = v.x; w1col[4*q+1] = v.y;
            w1col[4*q+2] = v.z; w1col[4*q+3] = v.w;
        }
    }

    for (int i = blockIdx.x * 4 + wv; i < 100000; i += gridDim.x * 4) {
        float e = emb0[i * 32 + (lane & 31)];
        float a0 = 0.f, a1 = 0.f, a2 = 0.f, a3 = 0.f;
        #pragma unroll
        for (int dd = 0; dd < 32; dd += 4) {
            a0 = fmaf(rl_f(e, dd + 0), w1col[dd + 0], a0);
            a1 = fmaf(rl_f(e, dd + 1), w1col[dd + 1], a1);
            a2 = fmaf(rl_f(e, dd + 2), w1col[dd + 2], a2);
            a3 = fmaf(rl_f(e, dd + 3), w1col[dd + 3], a3);
        }
        g_E1_0b[i * 64 + lane] = __float2bfloat16((a0 + a1) + (a2 + a3));
    }
}

// ---------------------------------------------------------------------------
// Phase 1: 8 rows/wave, ALL gathers batched in one latency exposure.
// __launch_bounds__(256,4) licenses 128 VGPRs so ~60 loads stay in flight
// (R7's batch failed at VGPR=72 — compiler chunked the loads).
// ---------------------------------------------------------------------------
__global__ __launch_bounds__(256, 4) void phase1_kernel(
    const float* __restrict__ x,
    const float* __restrict__ emb0, const float* __restrict__ lin0,
    const float* __restrict__ emb1, const float* __restrict__ lin1,
    const float* __restrict__ emb2, const float* __restrict__ lin2,
    const float* __restrict__ emb3, const float* __restrict__ lin3,
    const float* __restrict__ cont_w, const float* __restrict__ cont_b,
    const float* __restrict__ clin_w, const float* __restrict__ clin_b,
    const float* __restrict__ fin_bias,
    float* __restrict__ fm_out)
{
    __shared__ float lsum[64], lsq[64];

    int tid  = threadIdx.x;
    int lane = tid & 63;
    int wv   = tid >> 6;
    int d    = lane & 31;
    bool lo  = lane < 32;

    if (tid < 64) { lsum[tid] = 0.f; lsq[tid] = 0.f; }
    __syncthreads();

    float uk[8];
    #pragma unroll
    for (int j = 0; j < 8; ++j) uk[j] = g_U[j * 64 + lane];
    float vbk = g_Vb[lane];

    float p1[8], p2[8], fb = 0.f;
    if (lo) {
        #pragma unroll
        for (int j = 0; j < 8; ++j) { p1[j] = cont_w[j * 32 + d]; p2[j] = cont_b[j * 32 + d]; }
    } else {
        #pragma unroll
        for (int j = 0; j < 8; ++j) { p1[j] = clin_w[j * 32 + d]; p2[j] = clin_b[j * 32 + d]; }
        fb = fin_bias[d];
    }

    const float* T0 = lo ? emb0 : lin0;
    const float* T1 = lo ? emb1 : lin1;
    const float* T2 = lo ? emb2 : lin2;
    const float* T3 = lo ? emb3 : lin3;

    int gw   = blockIdx.x * 4 + wv;        // 0..25599
    int base = gw * 8;

    // x-slab: rows 0-3 in xa, rows 4-7 in xb
    float xa = (lane < 48) ? x[base * 12 + lane] : 0.f;
    float xb = (lane < 48) ? x[base * 12 + 48 + lane] : 0.f;

    // all 32 indices via readlane
    int i0[8], i1[8], i2[8], i3[8];
    #pragma unroll
    for (int it = 0; it < 8; ++it) {
        float s = (it < 4) ? xa : xb;
        int   f = (it < 4) ? it * 12 : it * 12 - 48;
        i0[it] = clampi((int)rl_f(s, f + 0), 99999);
        i1[it] = clampi((int)rl_f(s, f + 1), 999);
        i2[it] = clampi((int)rl_f(s, f + 2), 99);
        i3[it] = clampi((int)rl_f(s, f + 3), 49);
    }

    // batch-issue ALL gathers: 8 rows x (4 table + E0 + t1..t3)
    float ga[8], gb[8], gc[8], gd[8], t1[8], t2[8], t3[8];
    unsigned short e0u[8];
    #pragma unroll
    for (int it = 0; it < 8; ++it) {
        ga[it]  = T0[i0[it] * 32 + d];
        gb[it]  = T1[i1[it] * 32 + d];
        gc[it]  = T2[i2[it] * 32 + d];
        gd[it]  = T3[i3[it] * 32 + d];
        e0u[it] = ((const unsigned short*)g_E1_0b)[i0[it] * 64 + lane];
        t1[it]  = g_E1_1[i1[it] * 64 + lane];
        t2[it]  = g_E1_2[i2[it] * 64 + lane];
        t3[it]  = g_E1_3[i3[it] * 64 + lane];
    }

    float ss = 0.f, qq = 0.f;

    #pragma unroll
    for (int it = 0; it < 8; ++it) {
        int r  = base + it;
        float xs = (it < 4) ? xa : xb;
        int   fo = ((it < 4) ? it * 12 : it * 12 - 48) + 4;
        float xc[8];
        #pragma unroll
        for (int j = 0; j < 8; ++j) xc[j] = rl_f(xs, fo + j);

        float half_val;
        if (lo) {
            float s0 = ga[it] + gb[it], s1 = gc[it] + gd[it];
            float q0 = fmaf(ga[it], ga[it], gb[it] * gb[it]);
            float q1 = fmaf(gc[it], gc[it], gd[it] * gd[it]);
            #pragma unroll
            for (int j = 0; j < 8; ++j) {
                float ce = fmaf(xc[j], p1[j], p2[j]);
                if (j & 1) { s1 += ce; q1 = fmaf(ce, ce, q1); }
                else       { s0 += ce; q0 = fmaf(ce, ce, q0); }
            }
            float s = s0 + s1;
            half_val = 0.5f * (s * s - (q0 + q1));       // interaction
        } else {
            float l0 = ga[it] + gb[it] + fb, l1 = gc[it] + gd[it];
            #pragma unroll
            for (int j = 0; j < 8; ++j) {
                if (j & 1) l1 = fmaf(xc[j], p1[j], l1 + p2[j]);
                else       l0 = fmaf(xc[j], p1[j], l0 + p2[j]);
            }
            half_val = l0 + l1;                          // linear
        }
        float other = __shfl(half_val, lane | 32);
        if (lo) fm_out[r * 32 + d] = half_val + other;

        float h1 = ((vbk + us2f(e0u[it])) + (t1[it] + t2[it])) + t3[it];
        #pragma unroll
        for (int j = 0; j < 8; ++j) h1 = fmaf(xc[j], uk[j], h1);

        g_h1p[r * 64 + lane] = __float2bfloat16(h1);
        ss += h1;
        qq = fmaf(h1, h1, qq);
    }

    atomicAdd(&lsum[lane], ss);
    atomicAdd(&lsq[lane], qq);
    __syncthreads();
    if (tid < 64) {
        atomicAdd(&g_stats[tid], lsum[tid]);        // sum1
        atomicAdd(&g_stats[64 + tid], lsq[tid]);    // sumsq1
    }
}

// ---------------------------------------------------------------------------
// bnprep1: fold BN1 stats into per-channel affine (a1, c1)
// ---------------------------------------------------------------------------
__global__ __launch_bounds__(64) void bnprep1_kernel(
    const float* __restrict__ g1, const float* __restrict__ beta1)
{
    int k = threadIdx.x;
    float mu  = g_stats[k] * N_INV;
    float var = g_stats[64 + k] * N_INV - mu * mu;
    float a   = g1[k] * rsqrtf(var + 1e-5f);
    g_bn1[k]      = a;
    g_bn1[64 + k] = beta1[k] - a * mu;
}

// ---------------------------------------------------------------------------
// Phase 2 (row-per-lane, register-lean): two 32-channel half-passes so only
// y[32] + acc[32] are live. Uniform w2 reads -> scalar loads. No LDS.
// ---------------------------------------------------------------------------
__global__ __launch_bounds__(256) void phase2_kernel(
    const float* __restrict__ w2, const float* __restrict__ b2)
{
    int tid  = threadIdx.x;
    int lane = tid & 63;
    int wv   = tid >> 6;
    size_t row = (size_t)(blockIdx.x * 4 + wv) * 64 + lane;

    const uint4* hrow = (const uint4*)(g_h1p + row * 64);

    float acc[32];
    #pragma unroll
    for (int m = 0; m < 32; ++m) acc[m] = 0.f;

    #pragma unroll
    for (int half = 0; half < 2; ++half) {
        uint4 u[4];
        #pragma unroll
        for (int q = 0; q < 4; ++q) u[q] = hrow[half * 4 + q];

        float y[32];
        #pragma unroll
        for (int q = 0; q < 4; ++q) {
            unsigned int w4[4] = {u[q].x, u[q].y, u[q].z, u[q].w};
            #pragma unroll
            for (int j = 0; j < 4; ++j) {
                int i  = q * 4 + j;
                int ch = half * 32 + 2 * i;
                float f0 = __uint_as_float(w4[j] << 16);
                float f1 = __uint_as_float(w4[j] & 0xffff0000u);
                y[2*i]     = fmaxf(0.f, fmaf(g_bn1[ch],     f0, g_bn1[64 + ch]));
                y[2*i + 1] = fmaxf(0.f, fmaf(g_bn1[ch + 1], f1, g_bn1[64 + ch + 1]));
            }
        }

        #pragma unroll
        for (int m = 0; m < 32; ++m) {
            const float* wr = w2 + m * 64 + half * 32;   // uniform -> scalar
            float a0 = 0.f, a1 = 0.f, a2 = 0.f, a3 = 0.f;
            #pragma unroll
            for (int k = 0; k < 32; k += 4) {
                a0 = fmaf(y[k + 0], wr[k + 0], a0);
                a1 = fmaf(y[k + 1], wr[k + 1], a1);
                a2 = fmaf(y[k + 2], wr[k + 2], a2);
                a3 = fmaf(y[k + 3], wr[k + 3], a3);
            }
            acc[m] += (a0 + a1) + (a2 + a3);
        }
    }

    uint4 o[4];
    unsigned int* ow = (unsigned int*)o;
    #pragma unroll
    for (int i = 0; i < 16; ++i) {
        unsigned int lo16 = (unsigned int)__bfloat16_as_ushort(__float2bfloat16(acc[2*i]     + b2[2*i]));
        unsigned int hi16 = (unsigned int)__bfloat16_as_ushort(__float2bfloat16(acc[2*i + 1] + b2[2*i + 1]));
        ow[i] = lo16 | (hi16 << 16);
    }
    uint4* orow = (uint4*)(g_h2p + row * 32);
    #pragma unroll
    for (int q = 0; q < 4; ++q) orow[q] = o[q];
}

// ---------------------------------------------------------------------------
// red2: streaming reduction of g_h2p -> per-channel sum/sumsq (layer-2 stats)
// ---------------------------------------------------------------------------
__global__ __launch_bounds__(256) void red2_kernel()
{
    __shared__ float ls[64];       // ls[ch]=sum, ls[32+ch]=sumsq
    int tid = threadIdx.x;
    if (tid < 64) ls[tid] = 0.f;
    __syncthreads();

    const unsigned int* p = (const unsigned int*)g_h2p;   // ROWS*16 uints
    int cp = tid & 15;                                    // channels 2cp, 2cp+1
    float s0 = 0.f, q0 = 0.f, s1 = 0.f, q1 = 0.f;
    for (int i = blockIdx.x * 256 + tid; i < ROWS * 16; i += 256 * 256) {
        unsigned int u = p[i];
        float f0 = __uint_as_float(u << 16);
        float f1 = __uint_as_float(u & 0xffff0000u);
        s0 += f0; q0 = fmaf(f0, f0, q0);
        s1 += f1; q1 = fmaf(f1, f1, q1);
    }
    atomicAdd(&ls[2*cp],      s0);
    atomicAdd(&ls[2*cp + 1],  s1);
    atomicAdd(&ls[32 + 2*cp], q0);
    atomicAdd(&ls[33 + 2*cp], q1);
    __syncthreads();
    if (tid < 32)            atomicAdd(&g_stats[128 + tid], ls[tid]);
    else if (tid < 64)       atomicAdd(&g_stats[160 + (tid - 32)], ls[tid]);
}

// ---------------------------------------------------------------------------
// bnprep2: fold BN2 stats into per-channel affine (a2, c2)
// ---------------------------------------------------------------------------
__global__ __launch_bounds__(32) void bnprep2_kernel(
    const float* __restrict__ g2, const float* __restrict__ beta2)
{
    int m = threadIdx.x;
    float mu  = g_stats[128 + m] * N_INV;
    float var = g_stats[160 + m] * N_INV - mu * mu;
    float a   = g2[m] * rsqrtf(var + 1e-5f);
    g_bn2[m]      = a;
    g_bn2[32 + m] = beta2[m] - a * mu;
}

// ---------------------------------------------------------------------------
// Phase 3 (row-per-lane, register-lean): out = fm + b_out + y2 @ w_out^T.
// ---------------------------------------------------------------------------
__global__ __launch_bounds__(256) void phase3_kernel(
    const float* __restrict__ w_out, const float* __restrict__ b_out,
    float* __restrict__ out)   // holds FM partial on entry
{
    int tid  = threadIdx.x;
    int lane = tid & 63;
    int wv   = tid >> 6;
    size_t row = (size_t)(blockIdx.x * 4 + wv) * 64 + lane;

    const uint4* hrow = (const uint4*)(g_h2p + row * 32);
    uint4 u[4];
    #pragma unroll
    for (int q = 0; q < 4; ++q) u[q] = hrow[q];

    float y2[32];
    #pragma unroll
    for (int q = 0; q < 4; ++q) {
        unsigned int w4[4] = {u[q].x, u[q].y, u[q].z, u[q].w};
        #pragma unroll
        for (int j = 0; j < 4; ++j) {
            int i = q * 4 + j;
            float f0 = __uint_as_float(w4[j] << 16);
            float f1 = __uint_as_float(w4[j] & 0xffff0000u);
            y2[2*i]     = fmaxf(0.f, fmaf(g_bn2[2*i],     f0, g_bn2[32 + 2*i]));
            y2[2*i + 1] = fmaxf(0.f, fmaf(g_bn2[2*i + 1], f1, g_bn2[32 + 2*i + 1]));
        }
    }

    float res[32];
    #pragma unroll
    for (int dd = 0; dd < 32; ++dd) {
        const float* wr = w_out + dd * 32;           // uniform -> scalar
        float a0 = b_out[dd], a1 = 0.f, a2 = 0.f, a3 = 0.f;
        #pragma unroll
        for (int k = 0; k < 32; k += 4) {
            a0 = fmaf(y2[k + 0], wr[k + 0], a0);
            a1 = fmaf(y2[k + 1], wr[k + 1], a1);
            a2 = fmaf(y2[k + 2], wr[k + 2], a2);
            a3 = fmaf(y2[k + 3], wr[k + 3], a3);
        }
        res[dd] = (a0 + a1) + (a2 + a3);
    }

    float4* orow = (float4*)(out + row * 32);
    #pragma unroll
    for (int q = 0; q < 8; ++q) {
        float4 f = orow[q];
        orow[q] = make_float4(res[4*q+0] + f.x, res[4*q+1] + f.y,
                              res[4*q+2] + f.z, res[4*q+3] + f.w);
    }
}

// ---------------------------------------------------------------------------
extern "C" void kernel_launch(void* const* d_in, const int* in_sizes, int n_in,
                              void* d_out, int out_size, void* d_ws, size_t ws_size,
                              hipStream_t stream) {
    (void)in_sizes; (void)n_in; (void)out_size; (void)d_ws; (void)ws_size;

    // setup_inputs() dict order (emb/lin interleaved!) — all float32
    const float* x       = (const float*)d_in[0];
    const float* emb0    = (const float*)d_in[1];
    const float* lin0    = (const float*)d_in[2];
    const float* emb1    = (const float*)d_in[3];
    const float* lin1    = (const float*)d_in[4];
    const float* emb2    = (const float*)d_in[5];
    const float* lin2    = (const float*)d_in[6];
    const float* emb3    = (const float*)d_in[7];
    const float* lin3    = (const float*)d_in[8];
    const float* cont_w  = (const float*)d_in[9];
    const float* cont_b  = (const float*)d_in[10];
    const float* clin_w  = (const float*)d_in[11];
    const float* clin_b  = (const float*)d_in[12];
    const float* fin_bias= (const float*)d_in[13];
    const float* w1      = (const float*)d_in[14];
    const float* b1      = (const float*)d_in[15];
    const float* g1      = (const float*)d_in[16];
    const float* beta1   = (const float*)d_in[17];
    const float* w2      = (const float*)d_in[18];
    const float* b2      = (const float*)d_in[19];
    const float* g2      = (const float*)d_in[20];
    const float* beta2   = (const float*)d_in[21];
    const float* w_out   = (const float*)d_in[22];
    const float* b_out   = (const float*)d_in[23];

    float* outp = (float*)d_out;               // also stages the FM partial

    hipLaunchKernelGGL(precompute_kernel, dim3(1151), dim3(64), 0, stream,
                       emb1, emb2, emb3, cont_w, cont_b, w1, b1);

    hipLaunchKernelGGL(e10_kernel, dim3(1600), dim3(256), 0, stream, emb0, w1);

    hipLaunchKernelGGL(phase1_kernel, dim3(6400), dim3(256), 0, stream,
                       x, emb0, lin0, emb1, lin1, emb2, lin2, emb3, lin3,
                       cont_w, cont_b, clin_w, clin_b, fin_bias,
                       outp);

    hipLaunchKernelGGL(bnprep1_kernel, dim3(1), dim3(64), 0, stream, g1, beta1);

    hipLaunchKernelGGL(phase2_kernel, dim3(800), dim3(256), 0, stream, w2, b2);

    hipLaunchKernelGGL(red2_kernel, dim3(256), dim3(256), 0, stream);

    hipLaunchKernelGGL(bnprep2_kernel, dim3(1), dim3(32), 0, stream, g2, beta2);

    hipLaunchKernelGGL(phase3_kernel, dim3(800), dim3(256), 0, stream,
                       w_out, b_out, outp);
}

// Round 10
// 335.862 us; speedup vs baseline: 1.3115x; 1.3115x over previous
//
#include <hip/hip_runtime.h>
#include <hip/hip_bf16.h>

typedef __hip_bfloat16 bf16;

#define ROWS 204800
#define N_INV (1.0f / 204800.0f)

// --- static device scratch (d_ws proved too small; never touch it) ----------
__device__ float g_stats[256];            // sum1[64] sumsq1[64] sum2[32] sumsq2[32]
__device__ bf16  g_E1_0b[100000 * 64];    // 12.8 MB: emb0 @ W1_0^T in bf16
__device__ float g_E1_1[1000 * 64];
__device__ float g_E1_2[100 * 64];
__device__ float g_E1_3[50 * 64];
__device__ float g_U[8 * 64];
__device__ float g_Vb[64];
__device__ bf16  g_h1p[ROWS * 64];        // 26.2 MB bf16 h1_pre
__device__ bf16  g_h2p[ROWS * 32];        // 13.1 MB bf16 h2_pre

__device__ __forceinline__ int clampi(int v, int hi) {
    return v < 0 ? 0 : (v > hi ? hi : v);
}
__device__ __forceinline__ float rl_f(float v, int l) {
    return __uint_as_float((unsigned int)__builtin_amdgcn_readlane((int)__float_as_uint(v), l));
}
__device__ __forceinline__ float us2f(unsigned short u) {
    return __uint_as_float(((unsigned int)u) << 16);
}

// ---------------------------------------------------------------------------
// Kernel A: E1_t = emb_t @ W1_t^T (t=1..3), U = cont_w @ W1_cont^T,
// Vb = b1 + sum_j cont_b[j] @ W1_cont_j^T. Block 1150 zeroes the stat block.
// ---------------------------------------------------------------------------
__global__ __launch_bounds__(64) void precompute_kernel(
    const float* __restrict__ emb1, const float* __restrict__ emb2, const float* __restrict__ emb3,
    const float* __restrict__ cont_w, const float* __restrict__ cont_b,
    const float* __restrict__ w1, const float* __restrict__ b1)
{
    int b = blockIdx.x;
    int k = threadIdx.x;
    __shared__ float row[32];

    if (b < 1150) {
        const float* tab; float* out; int i, colOff;
        if (b < 1000)      { tab = emb1; out = g_E1_1; i = b;        colOff = 32; }
        else if (b < 1100) { tab = emb2; out = g_E1_2; i = b - 1000; colOff = 64; }
        else               { tab = emb3; out = g_E1_3; i = b - 1100; colOff = 96; }
        if (k < 32) row[k] = tab[i * 32 + k];
        __syncthreads();
        const float* wr = w1 + k * 384 + colOff;
        float acc = 0.f;
        #pragma unroll
        for (int d = 0; d < 32; ++d) acc = fmaf(row[d], wr[d], acc);
        out[i * 64 + k] = acc;
    } else {
        g_stats[k]       = 0.f;
        g_stats[k + 64]  = 0.f;
        g_stats[k + 128] = 0.f;
        g_stats[k + 192] = 0.f;

        float vb = b1[k];
        #pragma unroll
        for (int j = 0; j < 8; ++j) {
            const float* wr = w1 + k * 384 + (4 + j) * 32;
            float u = 0.f;
            #pragma unroll
            for (int d = 0; d < 32; ++d) {
                float w = wr[d];
                u  = fmaf(cont_w[j * 32 + d], w, u);
                vb = fmaf(cont_b[j * 32 + d], w, vb);
            }
            g_U[j * 64 + k] = u;
        }
        g_Vb[k] = vb;
    }
}

// ---------------------------------------------------------------------------
// e10: E1_0 = emb0 @ W1_0^T  (100000 x 64), stored bf16. Wave per row.
// ---------------------------------------------------------------------------
__global__ __launch_bounds__(256) void e10_kernel(
    const float* __restrict__ emb0, const float* __restrict__ w1)
{
    int lane = threadIdx.x & 63;
    int wv   = threadIdx.x >> 6;

    float w1col[32];
    {
        const float4* wr = (const float4*)(w1 + lane * 384);
        #pragma unroll
        for (int q = 0; q < 8; ++q) {
            float4 v = wr[q];
            w1col[4*q+0] = v.x; w1col[4*q+1] = v.y;
            w1col[4*q+2] = v.z; w1col[4*q+3] = v.w;
        }
    }

    for (int i = blockIdx.x * 4 + wv; i < 100000; i += gridDim.x * 4) {
        float e = emb0[i * 32 + (lane & 31)];
        float a0 = 0.f, a1 = 0.f, a2 = 0.f, a3 = 0.f;
        #pragma unroll
        for (int dd = 0; dd < 32; dd += 4) {
            a0 = fmaf(rl_f(e, dd + 0), w1col[dd + 0], a0);
            a1 = fmaf(rl_f(e, dd + 1), w1col[dd + 1], a1);
            a2 = fmaf(rl_f(e, dd + 2), w1col[dd + 2], a2);
            a3 = fmaf(rl_f(e, dd + 3), w1col[dd + 3], a3);
        }
        g_E1_0b[i * 64 + lane] = __float2bfloat16((a0 + a1) + (a2 + a3));
    }
}

// ---------------------------------------------------------------------------
// Phase 1: R8 structure (16 rows/wave, groups of 4) + 2-slot group pipeline:
// group g+1's 32 gathers issue before group g's compute. All x/indices are
// available up front, so partial vmcnt waits can overlap latency.
// ---------------------------------------------------------------------------
__global__ __launch_bounds__(256) void phase1_kernel(
    const float* __restrict__ x,
    const float* __restrict__ emb0, const float* __restrict__ lin0,
    const float* __restrict__ emb1, const float* __restrict__ lin1,
    const float* __restrict__ emb2, const float* __restrict__ lin2,
    const float* __restrict__ emb3, const float* __restrict__ lin3,
    const float* __restrict__ cont_w, const float* __restrict__ cont_b,
    const float* __restrict__ clin_w, const float* __restrict__ clin_b,
    const float* __restrict__ fin_bias,
    float* __restrict__ fm_out)
{
    __shared__ float lsum[64], lsq[64];

    int tid  = threadIdx.x;
    int lane = tid & 63;
    int wv   = tid >> 6;
    int d    = lane & 31;
    bool lo  = lane < 32;

    if (tid < 64) { lsum[tid] = 0.f; lsq[tid] = 0.f; }
    __syncthreads();

    float uk[8];
    #pragma unroll
    for (int j = 0; j < 8; ++j) uk[j] = g_U[j * 64 + lane];
    float vbk = g_Vb[lane];

    float p1[8], p2[8], fb = 0.f;
    if (lo) {
        #pragma unroll
        for (int j = 0; j < 8; ++j) { p1[j] = cont_w[j * 32 + d]; p2[j] = cont_b[j * 32 + d]; }
    } else {
        #pragma unroll
        for (int j = 0; j < 8; ++j) { p1[j] = clin_w[j * 32 + d]; p2[j] = clin_b[j * 32 + d]; }
        fb = fin_bias[d];
    }

    const float* T0 = lo ? emb0 : lin0;
    const float* T1 = lo ? emb1 : lin1;
    const float* T2 = lo ? emb2 : lin2;
    const float* T3 = lo ? emb3 : lin3;

    int gw   = blockIdx.x * 4 + wv;        // 0..12799
    int base = gw * 16;

    // all 4 x-slabs up front (independent, coalesced)
    float xs[4];
    #pragma unroll
    for (int g = 0; g < 4; ++g)
        xs[g] = (lane < 48) ? x[(base + 4 * g) * 12 + lane] : 0.f;

    // double-buffered gather slots
    float ga[2][4], gb[2][4], gc[2][4], gd[2][4], t1[2][4], t2[2][4], t3[2][4];
    unsigned short e0u[2][4];

    auto issue = [&](int g, int s) {
        #pragma unroll
        for (int t = 0; t < 4; ++t) {
            int f  = t * 12;
            int i0 = clampi((int)rl_f(xs[g], f + 0), 99999);
            int i1 = clampi((int)rl_f(xs[g], f + 1), 999);
            int i2 = clampi((int)rl_f(xs[g], f + 2), 99);
            int i3 = clampi((int)rl_f(xs[g], f + 3), 49);
            ga[s][t]  = T0[i0 * 32 + d];
            gb[s][t]  = T1[i1 * 32 + d];
            gc[s][t]  = T2[i2 * 32 + d];
            gd[s][t]  = T3[i3 * 32 + d];
            e0u[s][t] = ((const unsigned short*)g_E1_0b)[i0 * 64 + lane];
            t1[s][t]  = g_E1_1[i1 * 64 + lane];
            t2[s][t]  = g_E1_2[i2 * 64 + lane];
            t3[s][t]  = g_E1_3[i3 * 64 + lane];
        }
    };

    issue(0, 0);

    float ss = 0.f, qq = 0.f;

    #pragma unroll
    for (int g = 0; g < 4; ++g) {
        int s = g & 1;
        if (g < 3) issue(g + 1, (g + 1) & 1);

        #pragma unroll
        for (int t = 0; t < 4; ++t) {
            int r  = base + 4 * g + t;
            int fo = t * 12 + 4;
            float xc[8];
            #pragma unroll
            for (int j = 0; j < 8; ++j) xc[j] = rl_f(xs[g], fo + j);

            float va = ga[s][t], vb = gb[s][t], vc = gc[s][t], vd = gd[s][t];

            float half_val;
            if (lo) {
                float s0 = va + vb, s1 = vc + vd;
                float q0 = fmaf(va, va, vb * vb);
                float q1 = fmaf(vc, vc, vd * vd);
                #pragma unroll
                for (int j = 0; j < 8; ++j) {
                    float ce = fmaf(xc[j], p1[j], p2[j]);
                    if (j & 1) { s1 += ce; q1 = fmaf(ce, ce, q1); }
                    else       { s0 += ce; q0 = fmaf(ce, ce, q0); }
                }
                float sfull = s0 + s1;
                half_val = 0.5f * (sfull * sfull - (q0 + q1));   // interaction
            } else {
                float l0 = va + vb + fb, l1 = vc + vd;
                #pragma unroll
                for (int j = 0; j < 8; ++j) {
                    if (j & 1) l1 = fmaf(xc[j], p1[j], l1 + p2[j]);
                    else       l0 = fmaf(xc[j], p1[j], l0 + p2[j]);
                }
                half_val = l0 + l1;                              // linear
            }
            float other = __shfl(half_val, lane | 32);
            if (lo) fm_out[r * 32 + d] = half_val + other;

            float h1 = ((vbk + us2f(e0u[s][t])) + (t1[s][t] + t2[s][t])) + t3[s][t];
            #pragma unroll
            for (int j = 0; j < 8; ++j) h1 = fmaf(xc[j], uk[j], h1);

            g_h1p[r * 64 + lane] = __float2bfloat16(h1);
            ss += h1;
            qq = fmaf(h1, h1, qq);
        }
    }

    atomicAdd(&lsum[lane], ss);
    atomicAdd(&lsq[lane], qq);
    __syncthreads();
    if (tid < 64) {
        atomicAdd(&g_stats[tid], lsum[tid]);        // sum1
        atomicAdd(&g_stats[64 + tid], lsq[tid]);    // sumsq1
    }
}

// ---------------------------------------------------------------------------
// Phase 2 (row-per-lane + fused BN1 prep): block computes a1/c1 into LDS,
// then two 32-channel half-passes. Uniform w2 reads -> scalar loads.
// ---------------------------------------------------------------------------
__global__ __launch_bounds__(256) void phase2_kernel(
    const float* __restrict__ w2, const float* __restrict__ b2,
    const float* __restrict__ g1, const float* __restrict__ beta1)
{
    __shared__ float sa[64], sc[64];
    int tid  = threadIdx.x;
    if (tid < 64) {
        float mu  = g_stats[tid] * N_INV;
        float var = g_stats[64 + tid] * N_INV - mu * mu;
        float a   = g1[tid] * rsqrtf(var + 1e-5f);
        sa[tid] = a;
        sc[tid] = beta1[tid] - a * mu;
    }
    __syncthreads();

    int lane = tid & 63;
    int wv   = tid >> 6;
    size_t row = (size_t)(blockIdx.x * 4 + wv) * 64 + lane;

    const uint4* hrow = (const uint4*)(g_h1p + row * 64);

    float acc[32];
    #pragma unroll
    for (int m = 0; m < 32; ++m) acc[m] = 0.f;

    #pragma unroll
    for (int half = 0; half < 2; ++half) {
        uint4 u[4];
        #pragma unroll
        for (int q = 0; q < 4; ++q) u[q] = hrow[half * 4 + q];

        float y[32];
        #pragma unroll
        for (int q = 0; q < 4; ++q) {
            unsigned int w4[4] = {u[q].x, u[q].y, u[q].z, u[q].w};
            #pragma unroll
            for (int j = 0; j < 4; ++j) {
                int i  = q * 4 + j;
                int ch = half * 32 + 2 * i;
                float f0 = __uint_as_float(w4[j] << 16);
                float f1 = __uint_as_float(w4[j] & 0xffff0000u);
                y[2*i]     = fmaxf(0.f, fmaf(sa[ch],     f0, sc[ch]));
                y[2*i + 1] = fmaxf(0.f, fmaf(sa[ch + 1], f1, sc[ch + 1]));
            }
        }

        #pragma unroll
        for (int m = 0; m < 32; ++m) {
            const float* wr = w2 + m * 64 + half * 32;   // uniform -> scalar
            float a0 = 0.f, a1 = 0.f, a2 = 0.f, a3 = 0.f;
            #pragma unroll
            for (int k = 0; k < 32; k += 4) {
                a0 = fmaf(y[k + 0], wr[k + 0], a0);
                a1 = fmaf(y[k + 1], wr[k + 1], a1);
                a2 = fmaf(y[k + 2], wr[k + 2], a2);
                a3 = fmaf(y[k + 3], wr[k + 3], a3);
            }
            acc[m] += (a0 + a1) + (a2 + a3);
        }
    }

    uint4 o[4];
    unsigned int* ow = (unsigned int*)o;
    #pragma unroll
    for (int i = 0; i < 16; ++i) {
        unsigned int lo16 = (unsigned int)__bfloat16_as_ushort(__float2bfloat16(acc[2*i]     + b2[2*i]));
        unsigned int hi16 = (unsigned int)__bfloat16_as_ushort(__float2bfloat16(acc[2*i + 1] + b2[2*i + 1]));
        ow[i] = lo16 | (hi16 << 16);
    }
    uint4* orow = (uint4*)(g_h2p + row * 32);
    #pragma unroll
    for (int q = 0; q < 4; ++q) orow[q] = o[q];
}

// ---------------------------------------------------------------------------
// red2: streaming reduction of g_h2p -> per-channel sum/sumsq (layer-2 stats)
// ---------------------------------------------------------------------------
__global__ __launch_bounds__(256) void red2_kernel()
{
    __shared__ float ls[64];       // ls[ch]=sum, ls[32+ch]=sumsq
    int tid = threadIdx.x;
    if (tid < 64) ls[tid] = 0.f;
    __syncthreads();

    const unsigned int* p = (const unsigned int*)g_h2p;   // ROWS*16 uints
    int cp = tid & 15;                                    // channels 2cp, 2cp+1
    float s0 = 0.f, q0 = 0.f, s1 = 0.f, q1 = 0.f;
    for (int i = blockIdx.x * 256 + tid; i < ROWS * 16; i += 256 * 256) {
        unsigned int u = p[i];
        float f0 = __uint_as_float(u << 16);
        float f1 = __uint_as_float(u & 0xffff0000u);
        s0 += f0; q0 = fmaf(f0, f0, q0);
        s1 += f1; q1 = fmaf(f1, f1, q1);
    }
    atomicAdd(&ls[2*cp],      s0);
    atomicAdd(&ls[2*cp + 1],  s1);
    atomicAdd(&ls[32 + 2*cp], q0);
    atomicAdd(&ls[33 + 2*cp], q1);
    __syncthreads();
    if (tid < 32)            atomicAdd(&g_stats[128 + tid], ls[tid]);
    else if (tid < 64)       atomicAdd(&g_stats[160 + (tid - 32)], ls[tid]);
}

// ---------------------------------------------------------------------------
// Phase 3 (row-per-lane + fused BN2 prep): out = fm + b_out + y2 @ w_out^T.
// ---------------------------------------------------------------------------
__global__ __launch_bounds__(256) void phase3_kernel(
    const float* __restrict__ w_out, const float* __restrict__ b_out,
    const float* __restrict__ g2, const float* __restrict__ beta2,
    float* __restrict__ out)   // holds FM partial on entry
{
    __shared__ float sa[32], sc[32];
    int tid  = threadIdx.x;
    if (tid < 32) {
        float mu  = g_stats[128 + tid] * N_INV;
        float var = g_stats[160 + tid] * N_INV - mu * mu;
        float a   = g2[tid] * rsqrtf(var + 1e-5f);
        sa[tid] = a;
        sc[tid] = beta2[tid] - a * mu;
    }
    __syncthreads();

    int lane = tid & 63;
    int wv   = tid >> 6;
    size_t row = (size_t)(blockIdx.x * 4 + wv) * 64 + lane;

    const uint4* hrow = (const uint4*)(g_h2p + row * 32);
    uint4 u[4];
    #pragma unroll
    for (int q = 0; q < 4; ++q) u[q] = hrow[q];

    float y2[32];
    #pragma unroll
    for (int q = 0; q < 4; ++q) {
        unsigned int w4[4] = {u[q].x, u[q].y, u[q].z, u[q].w};
        #pragma unroll
        for (int j = 0; j < 4; ++j) {
            int i = q * 4 + j;
            float f0 = __uint_as_float(w4[j] << 16);
            float f1 = __uint_as_float(w4[j] & 0xffff0000u);
            y2[2*i]     = fmaxf(0.f, fmaf(sa[2*i],     f0, sc[2*i]));
            y2[2*i + 1] = fmaxf(0.f, fmaf(sa[2*i + 1], f1, sc[2*i + 1]));
        }
    }

    float res[32];
    #pragma unroll
    for (int dd = 0; dd < 32; ++dd) {
        const float* wr = w_out + dd * 32;           // uniform -> scalar
        float a0 = b_out[dd], a1 = 0.f, a2 = 0.f, a3 = 0.f;
        #pragma unroll
        for (int k = 0; k < 32; k += 4) {
            a0 = fmaf(y2[k + 0], wr[k + 0], a0);
            a1 = fmaf(y2[k + 1], wr[k + 1], a1);
            a2 = fmaf(y2[k + 2], wr[k + 2], a2);
            a3 = fmaf(y2[k + 3], wr[k + 3], a3);
        }
        res[dd] = (a0 + a1) + (a2 + a3);
    }

    float4* orow = (float4*)(out + row * 32);
    #pragma unroll
    for (int q = 0; q < 8; ++q) {
        float4 f = orow[q];
        orow[q] = make_float4(res[4*q+0] + f.x, res[4*q+1] + f.y,
                              res[4*q+2] + f.z, res[4*q+3] + f.w);
    }
}

// ---------------------------------------------------------------------------
extern "C" void kernel_launch(void* const* d_in, const int* in_sizes, int n_in,
                              void* d_out, int out_size, void* d_ws, size_t ws_size,
                              hipStream_t stream) {
    (void)in_sizes; (void)n_in; (void)out_size; (void)d_ws; (void)ws_size;

    // setup_inputs() dict order (emb/lin interleaved!) — all float32
    const float* x       = (const float*)d_in[0];
    const float* emb0    = (const float*)d_in[1];
    const float* lin0    = (const float*)d_in[2];
    const float* emb1    = (const float*)d_in[3];
    const float* lin1    = (const float*)d_in[4];
    const float* emb2    = (const float*)d_in[5];
    const float* lin2    = (const float*)d_in[6];
    const float* emb3    = (const float*)d_in[7];
    const float* lin3    = (const float*)d_in[8];
    const float* cont_w  = (const float*)d_in[9];
    const float* cont_b  = (const float*)d_in[10];
    const float* clin_w  = (const float*)d_in[11];
    const float* clin_b  = (const float*)d_in[12];
    const float* fin_bias= (const float*)d_in[13];
    const float* w1      = (const float*)d_in[14];
    const float* b1      = (const float*)d_in[15];
    const float* g1      = (const float*)d_in[16];
    const float* beta1   = (const float*)d_in[17];
    const float* w2      = (const float*)d_in[18];
    const float* b2      = (const float*)d_in[19];
    const float* g2      = (const float*)d_in[20];
    const float* beta2   = (const float*)d_in[21];
    const float* w_out   = (const float*)d_in[22];
    const float* b_out   = (const float*)d_in[23];

    float* outp = (float*)d_out;               // also stages the FM partial

    hipLaunchKernelGGL(precompute_kernel, dim3(1151), dim3(64), 0, stream,
                       emb1, emb2, emb3, cont_w, cont_b, w1, b1);

    hipLaunchKernelGGL(e10_kernel, dim3(1600), dim3(256), 0, stream, emb0, w1);

    hipLaunchKernelGGL(phase1_kernel, dim3(3200), dim3(256), 0, stream,
                       x, emb0, lin0, emb1, lin1, emb2, lin2, emb3, lin3,
                       cont_w, cont_b, clin_w, clin_b, fin_bias,
                       outp);

    hipLaunchKernelGGL(phase2_kernel, dim3(800), dim3(256), 0, stream,
                       w2, b2, g1, beta1);

    hipLaunchKernelGGL(red2_kernel, dim3(256), dim3(256), 0, stream);

    hipLaunchKernelGGL(phase3_kernel, dim3(800), dim3(256), 0, stream,
                       w_out, b_out, g2, beta2, outp);
}

// Round 11
// 328.873 us; speedup vs baseline: 1.3393x; 1.0213x over previous
//
#include <hip/hip_runtime.h>
#include <hip/hip_bf16.h>

typedef __hip_bfloat16 bf16;

#define ROWS 204800
#define N_INV (1.0f / 204800.0f)

// --- static device scratch (d_ws proved too small; never touch it) ----------
__device__ float g_stats[256];            // sum1[64] sumsq1[64] sum2[32] sumsq2[32]
__device__ bf16  g_E1_0b[100000 * 64];    // 12.8 MB: emb0 @ W1_0^T in bf16
__device__ float g_E1_1[1000 * 64];
__device__ float g_E1_2[100 * 64];
__device__ float g_E1_3[50 * 64];
__device__ float g_U[8 * 64];
__device__ float g_Vb[64];
__device__ bf16  g_h1p[ROWS * 64];        // 26.2 MB bf16 h1_pre
__device__ bf16  g_h2p[ROWS * 32];        // 13.1 MB bf16 h2_pre
__device__ bf16  g_fmp[ROWS * 32];        // 13.1 MB bf16 FM partial

__device__ __forceinline__ int clampi(int v, int hi) {
    return v < 0 ? 0 : (v > hi ? hi : v);
}
__device__ __forceinline__ float rl_f(float v, int l) {
    return __uint_as_float((unsigned int)__builtin_amdgcn_readlane((int)__float_as_uint(v), l));
}
__device__ __forceinline__ float us2f(unsigned short u) {
    return __uint_as_float(((unsigned int)u) << 16);
}

// ---------------------------------------------------------------------------
// Kernel A: E1_t = emb_t @ W1_t^T (t=1..3), U = cont_w @ W1_cont^T,
// Vb = b1 + sum_j cont_b[j] @ W1_cont_j^T. Block 1150 zeroes the stat block.
// ---------------------------------------------------------------------------
__global__ __launch_bounds__(64) void precompute_kernel(
    const float* __restrict__ emb1, const float* __restrict__ emb2, const float* __restrict__ emb3,
    const float* __restrict__ cont_w, const float* __restrict__ cont_b,
    const float* __restrict__ w1, const float* __restrict__ b1)
{
    int b = blockIdx.x;
    int k = threadIdx.x;
    __shared__ float row[32];

    if (b < 1150) {
        const float* tab; float* out; int i, colOff;
        if (b < 1000)      { tab = emb1; out = g_E1_1; i = b;        colOff = 32; }
        else if (b < 1100) { tab = emb2; out = g_E1_2; i = b - 1000; colOff = 64; }
        else               { tab = emb3; out = g_E1_3; i = b - 1100; colOff = 96; }
        if (k < 32) row[k] = tab[i * 32 + k];
        __syncthreads();
        const float* wr = w1 + k * 384 + colOff;
        float acc = 0.f;
        #pragma unroll
        for (int d = 0; d < 32; ++d) acc = fmaf(row[d], wr[d], acc);
        out[i * 64 + k] = acc;
    } else {
        g_stats[k]       = 0.f;
        g_stats[k + 64]  = 0.f;
        g_stats[k + 128] = 0.f;
        g_stats[k + 192] = 0.f;

        float vb = b1[k];
        #pragma unroll
        for (int j = 0; j < 8; ++j) {
            const float* wr = w1 + k * 384 + (4 + j) * 32;
            float u = 0.f;
            #pragma unroll
            for (int d = 0; d < 32; ++d) {
                float w = wr[d];
                u  = fmaf(cont_w[j * 32 + d], w, u);
                vb = fmaf(cont_b[j * 32 + d], w, vb);
            }
            g_U[j * 64 + k] = u;
        }
        g_Vb[k] = vb;
    }
}

// ---------------------------------------------------------------------------
// e10: E1_0 = emb0 @ W1_0^T (100000 x 64) bf16. TWO rows per wave-iteration:
// lanes 0-31 load row A, lanes 32-63 row B; two independent FMA chains.
// ---------------------------------------------------------------------------
__global__ __launch_bounds__(256) void e10_kernel(
    const float* __restrict__ emb0, const float* __restrict__ w1)
{
    int lane = threadIdx.x & 63;
    int wv   = threadIdx.x >> 6;
    int h    = lane >> 5;

    float w1col[32];
    {
        const float4* wr = (const float4*)(w1 + lane * 384);
        #pragma unroll
        for (int q = 0; q < 8; ++q) {
            float4 v = wr[q];
            w1col[4*q+0] = v.x; w1col[4*q+1] = v.y;
            w1col[4*q+2] = v.z; w1col[4*q+3] = v.w;
        }
    }

    for (int i = blockIdx.x * 8 + wv * 2; i < 100000; i += gridDim.x * 8) {
        int iA = i, iB = i + 1;
        float e = emb0[(h ? iB : iA) * 32 + (lane & 31)];

        float a0 = 0.f, a1 = 0.f, a2 = 0.f, a3 = 0.f;
        float b0 = 0.f, b1v = 0.f, b2v = 0.f, b3 = 0.f;
        #pragma unroll
        for (int dd = 0; dd < 32; dd += 4) {
            a0  = fmaf(rl_f(e, dd + 0),      w1col[dd + 0], a0);
            a1  = fmaf(rl_f(e, dd + 1),      w1col[dd + 1], a1);
            a2  = fmaf(rl_f(e, dd + 2),      w1col[dd + 2], a2);
            a3  = fmaf(rl_f(e, dd + 3),      w1col[dd + 3], a3);
            b0  = fmaf(rl_f(e, 32 + dd + 0), w1col[dd + 0], b0);
            b1v = fmaf(rl_f(e, 32 + dd + 1), w1col[dd + 1], b1v);
            b2v = fmaf(rl_f(e, 32 + dd + 2), w1col[dd + 2], b2v);
            b3  = fmaf(rl_f(e, 32 + dd + 3), w1col[dd + 3], b3);
        }
        g_E1_0b[iA * 64 + lane] = __float2bfloat16((a0 + a1) + (a2 + a3));
        g_E1_0b[iB * 64 + lane] = __float2bfloat16((b0 + b1v) + (b2v + b3));
    }
}

// ---------------------------------------------------------------------------
// Phase 1: R10 structure (16 rows/wave, groups of 4, 2-slot pipeline).
// FM partial now written bf16 to g_fmp (halves phase1 write traffic).
// ---------------------------------------------------------------------------
__global__ __launch_bounds__(256) void phase1_kernel(
    const float* __restrict__ x,
    const float* __restrict__ emb0, const float* __restrict__ lin0,
    const float* __restrict__ emb1, const float* __restrict__ lin1,
    const float* __restrict__ emb2, const float* __restrict__ lin2,
    const float* __restrict__ emb3, const float* __restrict__ lin3,
    const float* __restrict__ cont_w, const float* __restrict__ cont_b,
    const float* __restrict__ clin_w, const float* __restrict__ clin_b,
    const float* __restrict__ fin_bias)
{
    __shared__ float lsum[64], lsq[64];

    int tid  = threadIdx.x;
    int lane = tid & 63;
    int wv   = tid >> 6;
    int d    = lane & 31;
    bool lo  = lane < 32;

    if (tid < 64) { lsum[tid] = 0.f; lsq[tid] = 0.f; }
    __syncthreads();

    float uk[8];
    #pragma unroll
    for (int j = 0; j < 8; ++j) uk[j] = g_U[j * 64 + lane];
    float vbk = g_Vb[lane];

    float p1[8], p2[8], fb = 0.f;
    if (lo) {
        #pragma unroll
        for (int j = 0; j < 8; ++j) { p1[j] = cont_w[j * 32 + d]; p2[j] = cont_b[j * 32 + d]; }
    } else {
        #pragma unroll
        for (int j = 0; j < 8; ++j) { p1[j] = clin_w[j * 32 + d]; p2[j] = clin_b[j * 32 + d]; }
        fb = fin_bias[d];
    }

    const float* T0 = lo ? emb0 : lin0;
    const float* T1 = lo ? emb1 : lin1;
    const float* T2 = lo ? emb2 : lin2;
    const float* T3 = lo ? emb3 : lin3;

    int gw   = blockIdx.x * 4 + wv;        // 0..12799
    int base = gw * 16;

    float xs[4];
    #pragma unroll
    for (int g = 0; g < 4; ++g)
        xs[g] = (lane < 48) ? x[(base + 4 * g) * 12 + lane] : 0.f;

    float ga[2][4], gb[2][4], gc[2][4], gd[2][4], t1[2][4], t2[2][4], t3[2][4];
    unsigned short e0u[2][4];

    auto issue = [&](int g, int s) {
        #pragma unroll
        for (int t = 0; t < 4; ++t) {
            int f  = t * 12;
            int i0 = clampi((int)rl_f(xs[g], f + 0), 99999);
            int i1 = clampi((int)rl_f(xs[g], f + 1), 999);
            int i2 = clampi((int)rl_f(xs[g], f + 2), 99);
            int i3 = clampi((int)rl_f(xs[g], f + 3), 49);
            ga[s][t]  = T0[i0 * 32 + d];
            gb[s][t]  = T1[i1 * 32 + d];
            gc[s][t]  = T2[i2 * 32 + d];
            gd[s][t]  = T3[i3 * 32 + d];
            e0u[s][t] = ((const unsigned short*)g_E1_0b)[i0 * 64 + lane];
            t1[s][t]  = g_E1_1[i1 * 64 + lane];
            t2[s][t]  = g_E1_2[i2 * 64 + lane];
            t3[s][t]  = g_E1_3[i3 * 64 + lane];
        }
    };

    issue(0, 0);

    float ss = 0.f, qq = 0.f;

    #pragma unroll
    for (int g = 0; g < 4; ++g) {
        int s = g & 1;
        if (g < 3) issue(g + 1, (g + 1) & 1);

        #pragma unroll
        for (int t = 0; t < 4; ++t) {
            int r  = base + 4 * g + t;
            int fo = t * 12 + 4;
            float xc[8];
            #pragma unroll
            for (int j = 0; j < 8; ++j) xc[j] = rl_f(xs[g], fo + j);

            float va = ga[s][t], vb = gb[s][t], vc = gc[s][t], vd = gd[s][t];

            float half_val;
            if (lo) {
                float s0 = va + vb, s1 = vc + vd;
                float q0 = fmaf(va, va, vb * vb);
                float q1 = fmaf(vc, vc, vd * vd);
                #pragma unroll
                for (int j = 0; j < 8; ++j) {
                    float ce = fmaf(xc[j], p1[j], p2[j]);
                    if (j & 1) { s1 += ce; q1 = fmaf(ce, ce, q1); }
                    else       { s0 += ce; q0 = fmaf(ce, ce, q0); }
                }
                float sfull = s0 + s1;
                half_val = 0.5f * (sfull * sfull - (q0 + q1));   // interaction
            } else {
                float l0 = va + vb + fb, l1 = vc + vd;
                #pragma unroll
                for (int j = 0; j < 8; ++j) {
                    if (j & 1) l1 = fmaf(xc[j], p1[j], l1 + p2[j]);
                    else       l0 = fmaf(xc[j], p1[j], l0 + p2[j]);
                }
                half_val = l0 + l1;                              // linear
            }
            float other = __shfl(half_val, lane | 32);
            if (lo) g_fmp[r * 32 + d] = __float2bfloat16(half_val + other);

            float h1 = ((vbk + us2f(e0u[s][t])) + (t1[s][t] + t2[s][t])) + t3[s][t];
            #pragma unroll
            for (int j = 0; j < 8; ++j) h1 = fmaf(xc[j], uk[j], h1);

            g_h1p[r * 64 + lane] = __float2bfloat16(h1);
            ss += h1;
            qq = fmaf(h1, h1, qq);
        }
    }

    atomicAdd(&lsum[lane], ss);
    atomicAdd(&lsq[lane], qq);
    __syncthreads();
    if (tid < 64) {
        atomicAdd(&g_stats[tid], lsum[tid]);        // sum1
        atomicAdd(&g_stats[64 + tid], lsq[tid]);    // sumsq1
    }
}

// ---------------------------------------------------------------------------
// Phase 2 (row-per-lane + fused BN1 prep + fused layer-2 stats):
// computes h2 in registers, stats via chunked shfl_xor butterflies (red2 gone).
// ---------------------------------------------------------------------------
__global__ __launch_bounds__(256) void phase2_kernel(
    const float* __restrict__ w2, const float* __restrict__ b2,
    const float* __restrict__ g1, const float* __restrict__ beta1)
{
    __shared__ float sa[64], sc[64];
    __shared__ float ls[64];                 // ls[m]=sum2, ls[32+m]=sumsq2
    int tid  = threadIdx.x;
    if (tid < 64) {
        float mu  = g_stats[tid] * N_INV;
        float var = g_stats[64 + tid] * N_INV - mu * mu;
        float a   = g1[tid] * rsqrtf(var + 1e-5f);
        sa[tid] = a;
        sc[tid] = beta1[tid] - a * mu;
        ls[tid] = 0.f;
    }
    __syncthreads();

    int lane = tid & 63;
    int wv   = tid >> 6;
    size_t row = (size_t)(blockIdx.x * 4 + wv) * 64 + lane;

    const uint4* hrow = (const uint4*)(g_h1p + row * 64);

    float acc[32];
    #pragma unroll
    for (int m = 0; m < 32; ++m) acc[m] = 0.f;

    #pragma unroll
    for (int half = 0; half < 2; ++half) {
        uint4 u[4];
        #pragma unroll
        for (int q = 0; q < 4; ++q) u[q] = hrow[half * 4 + q];

        float y[32];
        #pragma unroll
        for (int q = 0; q < 4; ++q) {
            unsigned int w4[4] = {u[q].x, u[q].y, u[q].z, u[q].w};
            #pragma unroll
            for (int j = 0; j < 4; ++j) {
                int i  = q * 4 + j;
                int ch = half * 32 + 2 * i;
                float f0 = __uint_as_float(w4[j] << 16);
                float f1 = __uint_as_float(w4[j] & 0xffff0000u);
                y[2*i]     = fmaxf(0.f, fmaf(sa[ch],     f0, sc[ch]));
                y[2*i + 1] = fmaxf(0.f, fmaf(sa[ch + 1], f1, sc[ch + 1]));
            }
        }

        #pragma unroll
        for (int m = 0; m < 32; ++m) {
            const float* wr = w2 + m * 64 + half * 32;   // uniform -> scalar
            float a0 = 0.f, a1 = 0.f, a2 = 0.f, a3 = 0.f;
            #pragma unroll
            for (int k = 0; k < 32; k += 4) {
                a0 = fmaf(y[k + 0], wr[k + 0], a0);
                a1 = fmaf(y[k + 1], wr[k + 1], a1);
                a2 = fmaf(y[k + 2], wr[k + 2], a2);
                a3 = fmaf(y[k + 3], wr[k + 3], a3);
            }
            acc[m] += (a0 + a1) + (a2 + a3);
        }
    }

    // h2 = acc + b2; pack+store bf16
    #pragma unroll
    for (int m = 0; m < 32; ++m) acc[m] += b2[m];

    uint4 o[4];
    unsigned int* ow = (unsigned int*)o;
    #pragma unroll
    for (int i = 0; i < 16; ++i) {
        unsigned int lo16 = (unsigned int)__bfloat16_as_ushort(__float2bfloat16(acc[2*i]));
        unsigned int hi16 = (unsigned int)__bfloat16_as_ushort(__float2bfloat16(acc[2*i + 1]));
        ow[i] = lo16 | (hi16 << 16);
    }
    uint4* orow = (uint4*)(g_h2p + row * 32);
    #pragma unroll
    for (int q = 0; q < 4; ++q) orow[q] = o[q];

    // layer-2 stats: chunked 64-lane butterflies, then LDS, then global
    #pragma unroll
    for (int c0 = 0; c0 < 32; c0 += 8) {
        float s[8], q[8];
        #pragma unroll
        for (int j = 0; j < 8; ++j) { s[j] = acc[c0 + j]; q[j] = s[j] * s[j]; }
        #pragma unroll
        for (int off = 32; off >= 1; off >>= 1) {
            #pragma unroll
            for (int j = 0; j < 8; ++j) {
                s[j] += __shfl_xor(s[j], off);
                q[j] += __shfl_xor(q[j], off);
            }
        }
        if (lane == 0) {
            #pragma unroll
            for (int j = 0; j < 8; ++j) {
                atomicAdd(&ls[c0 + j],      s[j]);
                atomicAdd(&ls[32 + c0 + j], q[j]);
            }
        }
    }
    __syncthreads();
    if (tid < 32)       atomicAdd(&g_stats[128 + tid], ls[tid]);
    else if (tid < 64)  atomicAdd(&g_stats[160 + (tid - 32)], ls[tid]);
}

// ---------------------------------------------------------------------------
// Phase 3 (row-per-lane + fused BN2 prep): out = fm(bf16) + b_out + y2 @ w_out^T.
// Pure write to d_out (no RMW).
// ---------------------------------------------------------------------------
__global__ __launch_bounds__(256) void phase3_kernel(
    const float* __restrict__ w_out, const float* __restrict__ b_out,
    const float* __restrict__ g2, const float* __restrict__ beta2,
    float* __restrict__ out)
{
    __shared__ float sa[32], sc[32];
    int tid  = threadIdx.x;
    if (tid < 32) {
        float mu  = g_stats[128 + tid] * N_INV;
        float var = g_stats[160 + tid] * N_INV - mu * mu;
        float a   = g2[tid] * rsqrtf(var + 1e-5f);
        sa[tid] = a;
        sc[tid] = beta2[tid] - a * mu;
    }
    __syncthreads();

    int lane = tid & 63;
    int wv   = tid >> 6;
    size_t row = (size_t)(blockIdx.x * 4 + wv) * 64 + lane;

    const uint4* hrow = (const uint4*)(g_h2p + row * 32);
    const uint4* frow = (const uint4*)(g_fmp + row * 32);
    uint4 u[4], fm4[4];
    #pragma unroll
    for (int q = 0; q < 4; ++q) { u[q] = hrow[q]; fm4[q] = frow[q]; }

    float y2[32];
    #pragma unroll
    for (int q = 0; q < 4; ++q) {
        unsigned int w4[4] = {u[q].x, u[q].y, u[q].z, u[q].w};
        #pragma unroll
        for (int j = 0; j < 4; ++j) {
            int i = q * 4 + j;
            float f0 = __uint_as_float(w4[j] << 16);
            float f1 = __uint_as_float(w4[j] & 0xffff0000u);
            y2[2*i]     = fmaxf(0.f, fmaf(sa[2*i],     f0, sc[2*i]));
            y2[2*i + 1] = fmaxf(0.f, fmaf(sa[2*i + 1], f1, sc[2*i + 1]));
        }
    }

    float fmv[32];
    {
        const unsigned int* fw = (const unsigned int*)fm4;
        #pragma unroll
        for (int i = 0; i < 16; ++i) {
            fmv[2*i]     = __uint_as_float(fw[i] << 16);
            fmv[2*i + 1] = __uint_as_float(fw[i] & 0xffff0000u);
        }
    }

    float res[32];
    #pragma unroll
    for (int dd = 0; dd < 32; ++dd) {
        const float* wr = w_out + dd * 32;           // uniform -> scalar
        float a0 = fmv[dd] + b_out[dd], a1 = 0.f, a2 = 0.f, a3 = 0.f;
        #pragma unroll
        for (int k = 0; k < 32; k += 4) {
            a0 = fmaf(y2[k + 0], wr[k + 0], a0);
            a1 = fmaf(y2[k + 1], wr[k + 1], a1);
            a2 = fmaf(y2[k + 2], wr[k + 2], a2);
            a3 = fmaf(y2[k + 3], wr[k + 3], a3);
        }
        res[dd] = (a0 + a1) + (a2 + a3);
    }

    float4* orow = (float4*)(out + row * 32);
    #pragma unroll
    for (int q = 0; q < 8; ++q)
        orow[q] = make_float4(res[4*q+0], res[4*q+1], res[4*q+2], res[4*q+3]);
}

// ---------------------------------------------------------------------------
extern "C" void kernel_launch(void* const* d_in, const int* in_sizes, int n_in,
                              void* d_out, int out_size, void* d_ws, size_t ws_size,
                              hipStream_t stream) {
    (void)in_sizes; (void)n_in; (void)out_size; (void)d_ws; (void)ws_size;

    // setup_inputs() dict order (emb/lin interleaved!) — all float32
    const float* x       = (const float*)d_in[0];
    const float* emb0    = (const float*)d_in[1];
    const float* lin0    = (const float*)d_in[2];
    const float* emb1    = (const float*)d_in[3];
    const float* lin1    = (const float*)d_in[4];
    const float* emb2    = (const float*)d_in[5];
    const float* lin2    = (const float*)d_in[6];
    const float* emb3    = (const float*)d_in[7];
    const float* lin3    = (const float*)d_in[8];
    const float* cont_w  = (const float*)d_in[9];
    const float* cont_b  = (const float*)d_in[10];
    const float* clin_w  = (const float*)d_in[11];
    const float* clin_b  = (const float*)d_in[12];
    const float* fin_bias= (const float*)d_in[13];
    const float* w1      = (const float*)d_in[14];
    const float* b1      = (const float*)d_in[15];
    const float* g1      = (const float*)d_in[16];
    const float* beta1   = (const float*)d_in[17];
    const float* w2      = (const float*)d_in[18];
    const float* b2      = (const float*)d_in[19];
    const float* g2      = (const float*)d_in[20];
    const float* beta2   = (const float*)d_in[21];
    const float* w_out   = (const float*)d_in[22];
    const float* b_out   = (const float*)d_in[23];

    float* outp = (float*)d_out;

    hipLaunchKernelGGL(precompute_kernel, dim3(1151), dim3(64), 0, stream,
                       emb1, emb2, emb3, cont_w, cont_b, w1, b1);

    hipLaunchKernelGGL(e10_kernel, dim3(1600), dim3(256), 0, stream, emb0, w1);

    hipLaunchKernelGGL(phase1_kernel, dim3(3200), dim3(256), 0, stream,
                       x, emb0, lin0, emb1, lin1, emb2, lin2, emb3, lin3,
                       cont_w, cont_b, clin_w, clin_b, fin_bias);

    hipLaunchKernelGGL(phase2_kernel, dim3(800), dim3(256), 0, stream,
                       w2, b2, g1, beta1);

    hipLaunchKernelGGL(phase3_kernel, dim3(800), dim3(256), 0, stream,
                       w_out, b_out, g2, beta2, outp);
}